// Round 2
// baseline (1210.285 us; speedup 1.0000x reference)
//
#include <hip/hip_runtime.h>
#include <hip/hip_bf16.h>
#include <math.h>

#define NUM_EXPERTS 8
#define NTOK 8192
#define CDIM 1024
#define FDIM 4096
#define MAXSLOTS 17408   /* 16384 slots + 8*128 pad */
#define MAXTILES 136     /* 8 XCDs x 17 tiles */
#define TILES_PER_XCD 17

typedef __bf16 bf16x8 __attribute__((ext_vector_type(8)));
typedef float  f32x4  __attribute__((ext_vector_type(4)));

#define GPTR(p) ((const __attribute__((address_space(1))) unsigned int*)(p))
#define LPTR(p) ((__attribute__((address_space(3))) unsigned int*)(p))

__device__ __forceinline__ float gelu_exact(float v){
  return 0.5f * v * (1.0f + erff(v * 0.70710678118654752f));
}

// ---------------- router: logits -> top2 -> weights + counts ----------------
__global__ __launch_bounds__(256) void moe_router(
    const float* __restrict__ x, const float* __restrict__ gw,
    int2* __restrict__ topi, float2* __restrict__ topw, int* __restrict__ counts)
{
  int token = blockIdx.x * 4 + (threadIdx.x >> 6);
  int lane  = threadIdx.x & 63;
  int e = lane & 7, part = lane >> 3;
  const float* xr = x + (size_t)token * CDIM;
  float s = 0.f;
  int c0 = part * 128;
  for (int c = c0; c < c0 + 128; ++c) s += xr[c] * gw[c * 8 + e];
  s += __shfl_xor(s, 8); s += __shfl_xor(s, 16); s += __shfl_xor(s, 32);
  float m1 = s; int i1 = e;
  for (int off = 1; off < 8; off <<= 1){
    float ov = __shfl_xor(m1, off); int oi = __shfl_xor(i1, off);
    if (ov > m1 || (ov == m1 && oi < i1)){ m1 = ov; i1 = oi; }
  }
  float l2 = (e == i1) ? -INFINITY : s;
  float m2 = l2; int i2 = e;
  for (int off = 1; off < 8; off <<= 1){
    float ov = __shfl_xor(m2, off); int oi = __shfl_xor(i2, off);
    if (ov > m2 || (ov == m2 && oi < i2)){ m2 = ov; i2 = oi; }
  }
  if (lane == 0){
    float r = expf(m2 - m1);          // p2/p1
    float wa = 1.f / (1.f + r);
    topi[token] = make_int2(i1, i2);
    topw[token] = make_float2(wa, 1.f - wa);
    atomicAdd(&counts[i1], 1);
    atomicAdd(&counts[i2], 1);
  }
}

// ---------------- x fp32 -> bf16 ----------------
__global__ __launch_bounds__(256) void convert_x_kernel(
    const float* __restrict__ x, __hip_bfloat16* __restrict__ xb)
{
  int i = (blockIdx.x * 256 + threadIdx.x) * 4;
  float4 v = *(const float4*)(x + i);
  union { __hip_bfloat16 hh[4]; ushort4 u; } cv;
  cv.hh[0] = __float2bfloat16(v.x);
  cv.hh[1] = __float2bfloat16(v.y);
  cv.hh[2] = __float2bfloat16(v.z);
  cv.hh[3] = __float2bfloat16(v.w);
  *(ushort4*)(xb + i) = cv.u;
}

// ---------------- weight transpose+convert: [z][R][Cc] fp32 -> [z][Cc][R] bf16 ----------------
__global__ __launch_bounds__(256) void transpose_bf16_kernel(
    const float* __restrict__ in, __hip_bfloat16* __restrict__ outp, int R, int Cc)
{
  __shared__ float tile[32][33];
  const size_t msz = (size_t)R * Cc;
  const float* inm = in + (size_t)blockIdx.z * msz;
  __hip_bfloat16* outm = outp + (size_t)blockIdx.z * msz;
  int r0 = blockIdx.y * 32, c0 = blockIdx.x * 32;
  int tx = threadIdx.x, ty = threadIdx.y;  // 32 x 8
  for (int yy = 0; yy < 32; yy += 8)
    tile[ty + yy][tx] = inm[(size_t)(r0 + ty + yy) * Cc + c0 + tx];
  __syncthreads();
  for (int yy = 0; yy < 32; yy += 8)
    outm[(size_t)(c0 + ty + yy) * R + r0 + tx] = __float2bfloat16(tile[tx][ty + yy]);
}

// ---------------- scan: expert offsets (128-aligned), tile table, pad fill ----------------
__global__ void scan_kernel(const int* __restrict__ counts, int* cursors, int* num_tiles,
    int* tile_expert, int* tile_slotbase, int* slot_token, float* slot_weight)
{
  int t = threadIdx.x;
  if (t == 0){
    int base = 0, T = 0;
    for (int e = 0; e < NUM_EXPERTS; ++e){
      cursors[e] = base;
      int nt = (counts[e] + 127) >> 7;
      for (int i = 0; i < nt; ++i){ tile_expert[T] = e; tile_slotbase[T] = base + i * 128; ++T; }
      base += nt << 7;
    }
    *num_tiles = T;
  }
  for (int i = t; i < MAXSLOTS; i += 256){ slot_token[i] = 0; slot_weight[i] = 0.f; }
}

// ---------------- assign (token,k) -> slot ----------------
__global__ void assign_kernel(const int2* __restrict__ topi, const float2* __restrict__ topw,
    int* cursors, int* slot_token, float* slot_weight)
{
  int token = blockIdx.x * 256 + threadIdx.x;
  int2 ii = topi[token];
  float2 ww = topw[token];
  int p0 = atomicAdd(&cursors[ii.x], 1);
  slot_token[p0] = token; slot_weight[p0] = ww.x;
  int p1 = atomicAdd(&cursors[ii.y], 1);
  slot_token[p1] = token; slot_weight[p1] = ww.y;
}

// ---------------- GEMM1: h = gelu(X[slots] @ w1[e]) ----------------
// 1D grid, XCD-contiguous tiles: xcd = L&7 handles tiles [xcd*17, xcd*17+17),
// all 32 n-blocks of a tile adjacent (co-resident on one XCD -> A k-slices
// fetched once per device, B per ~2 experts per XCD).
__global__ __launch_bounds__(256) void gemm1_kernel(
    const __hip_bfloat16* __restrict__ xbf, const __hip_bfloat16* __restrict__ w1t,
    __hip_bfloat16* __restrict__ h, const int* __restrict__ num_tiles,
    const int* __restrict__ tile_expert, const int* __restrict__ tile_slotbase,
    const int* __restrict__ slot_token)
{
  __shared__ __align__(16) __hip_bfloat16 As[128 * 64];
  __shared__ __align__(16) __hip_bfloat16 Bs[128 * 64];
  const int L = blockIdx.x;
  const int xcd = L & 7;
  const int j = L >> 3;            // 0..543
  const int tl = j >> 5;           // 0..16
  const int nb = j & 31;           // 0..31
  const int tm = xcd * TILES_PER_XCD + tl;
  if (tm >= *num_tiles) return;
  const int e = tile_expert[tm];
  const int sbase = tile_slotbase[tm];
  const int n0 = nb * 128;
  const int t = threadIdx.x;
  const int cl = t & 7;
  const __hip_bfloat16* w1e = w1t + (size_t)e * FDIM * CDIM;
  const __hip_bfloat16* aptr[4];
  const __hip_bfloat16* bptr[4];
#pragma unroll
  for (int jj = 0; jj < 4; ++jj){
    int r = jj * 32 + (t >> 3);
    int cg = cl ^ (r & 7);
    int tok = slot_token[sbase + r];
    aptr[jj] = xbf + (size_t)tok * CDIM + cg * 8;
    bptr[jj] = w1e + (size_t)(n0 + r) * CDIM + cg * 8;
  }
  char* asml = (char*)As + t * 16;
  char* bsml = (char*)Bs + t * 16;

  f32x4 acc[4][4] = {};
  const int lane = t & 63, wv = t >> 6;
  const int wm = (wv >> 1) * 64, wn = (wv & 1) * 64;
  const int lrow = lane & 15, quad = lane >> 4;

  for (int k0 = 0; k0 < CDIM; k0 += 64){
    __syncthreads();
#pragma unroll
    for (int jj = 0; jj < 4; ++jj){
      __builtin_amdgcn_global_load_lds(GPTR(aptr[jj] + k0), LPTR(asml + jj * 4096), 16, 0, 0);
      __builtin_amdgcn_global_load_lds(GPTR(bptr[jj] + k0), LPTR(bsml + jj * 4096), 16, 0, 0);
    }
    __syncthreads();
#pragma unroll
    for (int kk = 0; kk < 2; ++kk){
      bf16x8 af[4], bfr[4];
#pragma unroll
      for (int i = 0; i < 4; ++i){
        int ar = wm + i * 16 + lrow;
        int ac = (kk * 4 + quad) ^ (ar & 7);
        af[i] = *(const bf16x8*)((const char*)As + ar * 128 + ac * 16);
        int br = wn + i * 16 + lrow;
        int bc = (kk * 4 + quad) ^ (br & 7);
        bfr[i] = *(const bf16x8*)((const char*)Bs + br * 128 + bc * 16);
      }
#pragma unroll
      for (int i = 0; i < 4; ++i)
#pragma unroll
        for (int jj = 0; jj < 4; ++jj)
          acc[i][jj] = __builtin_amdgcn_mfma_f32_16x16x32_bf16(af[i], bfr[jj], acc[i][jj], 0, 0, 0);
    }
  }
#pragma unroll
  for (int i = 0; i < 4; ++i){
#pragma unroll
    for (int r = 0; r < 4; ++r){
      int row = wm + i * 16 + quad * 4 + r;
      __hip_bfloat16* hrow = h + (size_t)(sbase + row) * FDIM + n0 + wn;
#pragma unroll
      for (int jj = 0; jj < 4; ++jj)
        hrow[jj * 16 + lrow] = __float2bfloat16(gelu_exact(acc[i][jj][r]));
    }
  }
}

// ---------------- GEMM2: out[token] += w * (h[slots] @ w2[e]) ----------------
// 1D grid, XCD-contiguous tiles + K-split=2 (atomic accumulate), doubling
// resident blocks/CU for latency hiding.
__global__ __launch_bounds__(256) void gemm2_kernel(
    const __hip_bfloat16* __restrict__ h, const __hip_bfloat16* __restrict__ w2t,
    float* __restrict__ out, const int* __restrict__ num_tiles,
    const int* __restrict__ tile_expert, const int* __restrict__ tile_slotbase,
    const int* __restrict__ slot_token, const float* __restrict__ slot_weight)
{
  __shared__ __align__(16) __hip_bfloat16 As[128 * 64];
  __shared__ __align__(16) __hip_bfloat16 Bs[128 * 64];
  const int L = blockIdx.x;
  const int xcd = L & 7;
  const int j = L >> 3;            // 0..271
  const int tl = j >> 4;           // 0..16
  const int nb = (j >> 1) & 7;     // 0..7
  const int ks = j & 1;            // K-split half
  const int tm = xcd * TILES_PER_XCD + tl;
  if (tm >= *num_tiles) return;
  const int e = tile_expert[tm];
  const int sbase = tile_slotbase[tm];
  const int n0 = nb * 128;
  const int t = threadIdx.x;
  const int cl = t & 7;
  const __hip_bfloat16* w2e = w2t + (size_t)e * CDIM * FDIM;
  const __hip_bfloat16* aptr[4];
  const __hip_bfloat16* bptr[4];
#pragma unroll
  for (int jj = 0; jj < 4; ++jj){
    int r = jj * 32 + (t >> 3);
    int cg = cl ^ (r & 7);
    aptr[jj] = h   + (size_t)(sbase + r) * FDIM + cg * 8;
    bptr[jj] = w2e + (size_t)(n0 + r)   * FDIM + cg * 8;
  }
  char* asml = (char*)As + t * 16;
  char* bsml = (char*)Bs + t * 16;

  f32x4 acc[4][4] = {};
  const int lane = t & 63, wv = t >> 6;
  const int wm = (wv >> 1) * 64, wn = (wv & 1) * 64;
  const int lrow = lane & 15, quad = lane >> 4;

  const int kbeg = ks * (FDIM / 2);
  for (int k0 = kbeg; k0 < kbeg + FDIM / 2; k0 += 64){
    __syncthreads();
#pragma unroll
    for (int jj = 0; jj < 4; ++jj){
      __builtin_amdgcn_global_load_lds(GPTR(aptr[jj] + k0), LPTR(asml + jj * 4096), 16, 0, 0);
      __builtin_amdgcn_global_load_lds(GPTR(bptr[jj] + k0), LPTR(bsml + jj * 4096), 16, 0, 0);
    }
    __syncthreads();
#pragma unroll
    for (int kk = 0; kk < 2; ++kk){
      bf16x8 af[4], bfr[4];
#pragma unroll
      for (int i = 0; i < 4; ++i){
        int ar = wm + i * 16 + lrow;
        int ac = (kk * 4 + quad) ^ (ar & 7);
        af[i] = *(const bf16x8*)((const char*)As + ar * 128 + ac * 16);
        int br = wn + i * 16 + lrow;
        int bc = (kk * 4 + quad) ^ (br & 7);
        bfr[i] = *(const bf16x8*)((const char*)Bs + br * 128 + bc * 16);
      }
#pragma unroll
      for (int i = 0; i < 4; ++i)
#pragma unroll
        for (int jj = 0; jj < 4; ++jj)
          acc[i][jj] = __builtin_amdgcn_mfma_f32_16x16x32_bf16(af[i], bfr[jj], acc[i][jj], 0, 0, 0);
    }
  }
#pragma unroll
  for (int i = 0; i < 4; ++i){
#pragma unroll
    for (int r = 0; r < 4; ++r){
      int row = wm + i * 16 + quad * 4 + r;
      int slot = sbase + row;
      int tok = slot_token[slot];
      float wgt = slot_weight[slot];
      float* orow = out + (size_t)tok * CDIM + n0 + wn;
#pragma unroll
      for (int jj = 0; jj < 4; ++jj)
        atomicAdd(&orow[jj * 16 + lrow], wgt * acc[i][jj][r]);
    }
  }
}

// ---------------- slow-but-correct fallback (ws too small) ----------------
__global__ __launch_bounds__(256) void naive_kernel(
    const float* __restrict__ x, const float* __restrict__ w1, const float* __restrict__ w2,
    const int2* __restrict__ topi, const float2* __restrict__ topw, float* __restrict__ out)
{
  __shared__ float xs[CDIM];
  __shared__ float hs[FDIM];
  int token = blockIdx.x;
  int t = threadIdx.x;
  for (int i = t; i < CDIM; i += 256) xs[i] = x[(size_t)token * CDIM + i];
  float acc[4] = {0.f, 0.f, 0.f, 0.f};
  int2 ei = topi[token]; float2 ew = topw[token];
  int elist[2] = {ei.x, ei.y}; float wlist[2] = {ew.x, ew.y};
  for (int kk = 0; kk < 2; ++kk){
    int e = elist[kk]; float wgt = wlist[kk];
    __syncthreads();
    for (int f = t; f < FDIM; f += 256){
      const float* wcol = w1 + (size_t)e * CDIM * FDIM + f;
      float s = 0.f;
      for (int c = 0; c < CDIM; ++c) s += xs[c] * wcol[(size_t)c * FDIM];
      hs[f] = gelu_exact(s);
    }
    __syncthreads();
    for (int ii = 0; ii < 4; ++ii){
      int c = ii * 256 + t;
      const float* w2col = w2 + (size_t)e * FDIM * CDIM + c;
      float s = 0.f;
      for (int f = 0; f < FDIM; ++f) s += hs[f] * w2col[(size_t)f * CDIM];
      acc[ii] += wgt * s;
    }
  }
  for (int ii = 0; ii < 4; ++ii) out[(size_t)token * CDIM + ii * 256 + t] = acc[ii];
}

extern "C" void kernel_launch(void* const* d_in, const int* in_sizes, int n_in,
                              void* d_out, int out_size, void* d_ws, size_t ws_size,
                              hipStream_t stream)
{
  const float* x  = (const float*)d_in[0];
  const float* gw = (const float*)d_in[1];
  const float* w1 = (const float*)d_in[2];
  const float* w2 = (const float*)d_in[3];
  float* out = (float*)d_out;
  char* ws = (char*)d_ws;

  int*    counts        = (int*)(ws + 0);
  int*    cursors       = (int*)(ws + 32);
  int*    num_tiles     = (int*)(ws + 64);
  int*    tile_expert   = (int*)(ws + 256);
  int*    tile_slotbase = (int*)(ws + 1024);
  int2*   topi          = (int2*)(ws + 4096);
  float2* topw          = (float2*)(ws + 4096 + 65536);
  int*    slot_token    = (int*)(ws + 135168);
  float*  slot_weight   = (float*)(ws + 204800);
  const size_t XBF_OFF = 1u << 20;
  const size_t W1T_OFF = XBF_OFF + (size_t)NTOK * CDIM * 2;
  const size_t W2T_OFF = W1T_OFF + (size_t)NUM_EXPERTS * CDIM * FDIM * 2;
  const size_t H_OFF   = W2T_OFF + (size_t)NUM_EXPERTS * CDIM * FDIM * 2;
  const size_t NEED    = H_OFF + (size_t)MAXSLOTS * FDIM * 2;                  // ~295 MB
  __hip_bfloat16* xbf = (__hip_bfloat16*)(ws + XBF_OFF);
  __hip_bfloat16* w1t = (__hip_bfloat16*)(ws + W1T_OFF);
  __hip_bfloat16* w2t = (__hip_bfloat16*)(ws + W2T_OFF);
  __hip_bfloat16* h   = (__hip_bfloat16*)(ws + H_OFF);

  hipMemsetAsync(ws, 0, 4096, stream);
  hipMemsetAsync(d_out, 0, (size_t)out_size * sizeof(float), stream);

  moe_router<<<NTOK / 4, 256, 0, stream>>>(x, gw, topi, topw, counts);

  if (ws_size >= NEED){
    convert_x_kernel<<<NTOK * CDIM / (4 * 256), 256, 0, stream>>>(x, xbf);
    transpose_bf16_kernel<<<dim3(FDIM / 32, CDIM / 32, NUM_EXPERTS), dim3(32, 8), 0, stream>>>(w1, w1t, CDIM, FDIM);
    transpose_bf16_kernel<<<dim3(CDIM / 32, FDIM / 32, NUM_EXPERTS), dim3(32, 8), 0, stream>>>(w2, w2t, FDIM, CDIM);
    scan_kernel<<<1, 256, 0, stream>>>(counts, cursors, num_tiles, tile_expert, tile_slotbase, slot_token, slot_weight);
    assign_kernel<<<NTOK / 256, 256, 0, stream>>>(topi, topw, cursors, slot_token, slot_weight);
    gemm1_kernel<<<8 * TILES_PER_XCD * 32, 256, 0, stream>>>(xbf, w1t, h, num_tiles, tile_expert, tile_slotbase, slot_token);
    gemm2_kernel<<<8 * TILES_PER_XCD * 8 * 2, 256, 0, stream>>>(h, w2t, out, num_tiles, tile_expert, tile_slotbase, slot_token, slot_weight);
  } else {
    naive_kernel<<<NTOK, 256, 0, stream>>>(x, w1, w2, topi, topw, out);
  }
}

// Round 3
// 1135.595 us; speedup vs baseline: 1.0658x; 1.0658x over previous
//
#include <hip/hip_runtime.h>
#include <hip/hip_bf16.h>
#include <math.h>

#define NUM_EXPERTS 8
#define NTOK 8192
#define CDIM 1024
#define FDIM 4096
#define MAXSLOTS 17408   /* 16384 slots + 8*128 pad */
#define MAXTILES 136     /* 8 XCDs x 17 tiles */
#define TILES_PER_XCD 17

typedef __bf16 bf16x8 __attribute__((ext_vector_type(8)));
typedef float  f32x4  __attribute__((ext_vector_type(4)));

#define GPTR(p) ((const __attribute__((address_space(1))) unsigned int*)(p))
#define LPTR(p) ((__attribute__((address_space(3))) unsigned int*)(p))

__device__ __forceinline__ float gelu_exact(float v){
  return 0.5f * v * (1.0f + erff(v * 0.70710678118654752f));
}
__device__ __forceinline__ float bf2f(unsigned short u){
  union { unsigned int i; float f; } cv; cv.i = ((unsigned int)u) << 16; return cv.f;
}

// ---------------- router: logits -> top2 -> weights + counts ----------------
__global__ __launch_bounds__(256) void moe_router(
    const float* __restrict__ x, const float* __restrict__ gw,
    int2* __restrict__ topi, float2* __restrict__ topw, int* __restrict__ counts)
{
  int token = blockIdx.x * 4 + (threadIdx.x >> 6);
  int lane  = threadIdx.x & 63;
  int e = lane & 7, part = lane >> 3;
  const float* xr = x + (size_t)token * CDIM;
  float s = 0.f;
  int c0 = part * 128;
  for (int c = c0; c < c0 + 128; ++c) s += xr[c] * gw[c * 8 + e];
  s += __shfl_xor(s, 8); s += __shfl_xor(s, 16); s += __shfl_xor(s, 32);
  float m1 = s; int i1 = e;
  for (int off = 1; off < 8; off <<= 1){
    float ov = __shfl_xor(m1, off); int oi = __shfl_xor(i1, off);
    if (ov > m1 || (ov == m1 && oi < i1)){ m1 = ov; i1 = oi; }
  }
  float l2 = (e == i1) ? -INFINITY : s;
  float m2 = l2; int i2 = e;
  for (int off = 1; off < 8; off <<= 1){
    float ov = __shfl_xor(m2, off); int oi = __shfl_xor(i2, off);
    if (ov > m2 || (ov == m2 && oi < i2)){ m2 = ov; i2 = oi; }
  }
  if (lane == 0){
    float r = expf(m2 - m1);          // p2/p1
    float wa = 1.f / (1.f + r);
    topi[token] = make_int2(i1, i2);
    topw[token] = make_float2(wa, 1.f - wa);
    atomicAdd(&counts[i1], 1);
    atomicAdd(&counts[i2], 1);
  }
}

// ---------------- x fp32 -> bf16 ----------------
__global__ __launch_bounds__(256) void convert_x_kernel(
    const float* __restrict__ x, __hip_bfloat16* __restrict__ xb)
{
  int i = (blockIdx.x * 256 + threadIdx.x) * 4;
  float4 v = *(const float4*)(x + i);
  union { __hip_bfloat16 hh[4]; ushort4 u; } cv;
  cv.hh[0] = __float2bfloat16(v.x);
  cv.hh[1] = __float2bfloat16(v.y);
  cv.hh[2] = __float2bfloat16(v.z);
  cv.hh[3] = __float2bfloat16(v.w);
  *(ushort4*)(xb + i) = cv.u;
}

// ---------------- weight transpose+convert: [z][R][Cc] fp32 -> [z][Cc][R] bf16 ----
// 64x64 tiles, float4 global loads, LDS stride-66 (2-way = free), uint4 stores.
__global__ __launch_bounds__(256) void transpose_bf16_kernel(
    const float* __restrict__ in, __hip_bfloat16* __restrict__ outp, int R, int Cc)
{
  __shared__ __hip_bfloat16 tile[64 * 66];
  const size_t msz = (size_t)R * Cc;
  const float* inm = in + (size_t)blockIdx.z * msz;
  __hip_bfloat16* outm = outp + (size_t)blockIdx.z * msz;
  int r0 = blockIdx.y * 64, c0 = blockIdx.x * 64;
  int t = threadIdx.x;
  int r = t & 63, cseg = (t >> 6) * 16;       // wave-uniform cseg
  const float* src = inm + (size_t)(r0 + r) * Cc + c0 + cseg;
  float4 v0 = ((const float4*)src)[0];
  float4 v1 = ((const float4*)src)[1];
  float4 v2 = ((const float4*)src)[2];
  float4 v3 = ((const float4*)src)[3];
  float vv[16] = {v0.x,v0.y,v0.z,v0.w, v1.x,v1.y,v1.z,v1.w,
                  v2.x,v2.y,v2.z,v2.w, v3.x,v3.y,v3.z,v3.w};
#pragma unroll
  for (int k = 0; k < 16; ++k)
    tile[(cseg + k) * 66 + r] = __float2bfloat16(vv[k]);
  __syncthreads();
#pragma unroll
  for (int p = 0; p < 2; ++p){
    int cc = p * 32 + (t >> 3), ch = (t & 7) * 8;
    const unsigned short* rowp = (const unsigned short*)tile + cc * 66 + ch;  // 4B aligned
    unsigned int a = *(const unsigned int*)(rowp + 0);
    unsigned int b = *(const unsigned int*)(rowp + 2);
    unsigned int c = *(const unsigned int*)(rowp + 4);
    unsigned int d = *(const unsigned int*)(rowp + 6);
    *(uint4*)(outm + (size_t)(c0 + cc) * R + r0 + ch) = make_uint4(a, b, c, d);
  }
}

// ---------------- scan: expert offsets (128-aligned), tile table, pad fill ----------------
__global__ void scan_kernel(const int* __restrict__ counts, int* cursors, int* num_tiles,
    int* tile_expert, int* tile_slotbase, int* slot_token, float* slot_weight)
{
  int t = threadIdx.x;
  if (t == 0){
    int base = 0, T = 0;
    for (int e = 0; e < NUM_EXPERTS; ++e){
      cursors[e] = base;
      int nt = (counts[e] + 127) >> 7;
      for (int i = 0; i < nt; ++i){ tile_expert[T] = e; tile_slotbase[T] = base + i * 128; ++T; }
      base += nt << 7;
    }
    *num_tiles = T;
  }
  for (int i = t; i < MAXSLOTS; i += 256){ slot_token[i] = 0; slot_weight[i] = 0.f; }
}

// ---------------- assign (token,k) -> slot; record token -> slots ----------------
__global__ void assign_kernel(const int2* __restrict__ topi, const float2* __restrict__ topw,
    int* cursors, int* slot_token, float* slot_weight, int2* __restrict__ token_slots)
{
  int token = blockIdx.x * 256 + threadIdx.x;
  int2 ii = topi[token];
  float2 ww = topw[token];
  int p0 = atomicAdd(&cursors[ii.x], 1);
  slot_token[p0] = token; slot_weight[p0] = ww.x;
  int p1 = atomicAdd(&cursors[ii.y], 1);
  slot_token[p1] = token; slot_weight[p1] = ww.y;
  token_slots[token] = make_int2(p0, p1);
}

// ---------------- GEMM1: h = gelu(X[slots] @ w1[e]) ----------------
// XCD-contiguous 1D grid; LDS-coalesced epilogue (uint4 stores).
__global__ __launch_bounds__(256) void gemm1_kernel(
    const __hip_bfloat16* __restrict__ xbf, const __hip_bfloat16* __restrict__ w1t,
    __hip_bfloat16* __restrict__ h, const int* __restrict__ num_tiles,
    const int* __restrict__ tile_expert, const int* __restrict__ tile_slotbase,
    const int* __restrict__ slot_token)
{
  __shared__ __align__(16) char smem[32768];
  const int L = blockIdx.x;
  const int xcd = L & 7;
  const int j = L >> 3;            // 0..543
  const int tl = j >> 5;           // 0..16
  const int nb = j & 31;           // 0..31
  const int tm = xcd * TILES_PER_XCD + tl;
  if (tm >= *num_tiles) return;
  const int e = tile_expert[tm];
  const int sbase = tile_slotbase[tm];
  const int n0 = nb * 128;
  const int t = threadIdx.x;
  const int cl = t & 7;
  const __hip_bfloat16* w1e = w1t + (size_t)e * FDIM * CDIM;
  const __hip_bfloat16* aptr[4];
  const __hip_bfloat16* bptr[4];
#pragma unroll
  for (int jj = 0; jj < 4; ++jj){
    int r = jj * 32 + (t >> 3);
    int cg = cl ^ (r & 7);
    int tok = slot_token[sbase + r];
    aptr[jj] = xbf + (size_t)tok * CDIM + cg * 8;
    bptr[jj] = w1e + (size_t)(n0 + r) * CDIM + cg * 8;
  }
  char* asml = smem + t * 16;
  char* bsml = smem + 16384 + t * 16;

  f32x4 acc[4][4] = {};
  const int lane = t & 63, wv = t >> 6;
  const int wm = (wv >> 1) * 64, wn = (wv & 1) * 64;
  const int lrow = lane & 15, quad = lane >> 4;

  for (int k0 = 0; k0 < CDIM; k0 += 64){
    __syncthreads();
#pragma unroll
    for (int jj = 0; jj < 4; ++jj){
      __builtin_amdgcn_global_load_lds(GPTR(aptr[jj] + k0), LPTR(asml + jj * 4096), 16, 0, 0);
      __builtin_amdgcn_global_load_lds(GPTR(bptr[jj] + k0), LPTR(bsml + jj * 4096), 16, 0, 0);
    }
    __syncthreads();
#pragma unroll
    for (int kk = 0; kk < 2; ++kk){
      bf16x8 af[4], bfr[4];
#pragma unroll
      for (int i = 0; i < 4; ++i){
        int ar = wm + i * 16 + lrow;
        int ac = (kk * 4 + quad) ^ (ar & 7);
        af[i] = *(const bf16x8*)(smem + ar * 128 + ac * 16);
        int br = wn + i * 16 + lrow;
        int bc = (kk * 4 + quad) ^ (br & 7);
        bfr[i] = *(const bf16x8*)(smem + 16384 + br * 128 + bc * 16);
      }
#pragma unroll
      for (int i = 0; i < 4; ++i)
#pragma unroll
        for (int jj = 0; jj < 4; ++jj)
          acc[i][jj] = __builtin_amdgcn_mfma_f32_16x16x32_bf16(af[i], bfr[jj], acc[i][jj], 0, 0, 0);
    }
  }
  // ---- epilogue: gelu -> LDS (xor-swizzled) -> coalesced uint4 stores ----
  __syncthreads();
  __hip_bfloat16* Ct = (__hip_bfloat16*)smem;   // 128x128 bf16 = 32 KB
#pragma unroll
  for (int i = 0; i < 4; ++i)
#pragma unroll
    for (int r = 0; r < 4; ++r){
      int row = wm + i * 16 + quad * 4 + r;
#pragma unroll
      for (int jj = 0; jj < 4; ++jj){
        int col = wn + jj * 16 + lrow;
        int cc = (col >> 3) ^ (row & 15);
        Ct[row * 128 + cc * 8 + (col & 7)] = __float2bfloat16(gelu_exact(acc[i][jj][r]));
      }
    }
  __syncthreads();
#pragma unroll
  for (int v = 0; v < 8; ++v){
    int Lr = v * 256 + t;
    int row = Lr >> 4, cc = Lr & 15;
    int cs = cc ^ (row & 15);
    uint4 val = *(const uint4*)(Ct + row * 128 + cs * 8);
    *(uint4*)(h + (size_t)(sbase + row) * FDIM + n0 + cc * 8) = val;
  }
}

// ---------------- GEMM2: y[slot] = h[slot] @ w2[e]  (no atomics) ----------------
__global__ __launch_bounds__(256) void gemm2_kernel(
    const __hip_bfloat16* __restrict__ h, const __hip_bfloat16* __restrict__ w2t,
    __hip_bfloat16* __restrict__ y, const int* __restrict__ num_tiles,
    const int* __restrict__ tile_expert, const int* __restrict__ tile_slotbase)
{
  __shared__ __align__(16) char smem[32768];
  const int L = blockIdx.x;
  const int xcd = L & 7;
  const int j = L >> 3;            // 0..135
  const int tl = j >> 3;           // 0..16
  const int nb = j & 7;            // 0..7
  const int tm = xcd * TILES_PER_XCD + tl;
  if (tm >= *num_tiles) return;
  const int e = tile_expert[tm];
  const int sbase = tile_slotbase[tm];
  const int n0 = nb * 128;
  const int t = threadIdx.x;
  const int cl = t & 7;
  const __hip_bfloat16* w2e = w2t + (size_t)e * CDIM * FDIM;
  const __hip_bfloat16* aptr[4];
  const __hip_bfloat16* bptr[4];
#pragma unroll
  for (int jj = 0; jj < 4; ++jj){
    int r = jj * 32 + (t >> 3);
    int cg = cl ^ (r & 7);
    aptr[jj] = h   + (size_t)(sbase + r) * FDIM + cg * 8;
    bptr[jj] = w2e + (size_t)(n0 + r)   * FDIM + cg * 8;
  }
  char* asml = smem + t * 16;
  char* bsml = smem + 16384 + t * 16;

  f32x4 acc[4][4] = {};
  const int lane = t & 63, wv = t >> 6;
  const int wm = (wv >> 1) * 64, wn = (wv & 1) * 64;
  const int lrow = lane & 15, quad = lane >> 4;

  for (int k0 = 0; k0 < FDIM; k0 += 64){
    __syncthreads();
#pragma unroll
    for (int jj = 0; jj < 4; ++jj){
      __builtin_amdgcn_global_load_lds(GPTR(aptr[jj] + k0), LPTR(asml + jj * 4096), 16, 0, 0);
      __builtin_amdgcn_global_load_lds(GPTR(bptr[jj] + k0), LPTR(bsml + jj * 4096), 16, 0, 0);
    }
    __syncthreads();
#pragma unroll
    for (int kk = 0; kk < 2; ++kk){
      bf16x8 af[4], bfr[4];
#pragma unroll
      for (int i = 0; i < 4; ++i){
        int ar = wm + i * 16 + lrow;
        int ac = (kk * 4 + quad) ^ (ar & 7);
        af[i] = *(const bf16x8*)(smem + ar * 128 + ac * 16);
        int br = wn + i * 16 + lrow;
        int bc = (kk * 4 + quad) ^ (br & 7);
        bfr[i] = *(const bf16x8*)(smem + 16384 + br * 128 + bc * 16);
      }
#pragma unroll
      for (int i = 0; i < 4; ++i)
#pragma unroll
        for (int jj = 0; jj < 4; ++jj)
          acc[i][jj] = __builtin_amdgcn_mfma_f32_16x16x32_bf16(af[i], bfr[jj], acc[i][jj], 0, 0, 0);
    }
  }
  // ---- epilogue: LDS (xor-swizzled) -> coalesced uint4 stores to y ----
  __syncthreads();
  __hip_bfloat16* Ct = (__hip_bfloat16*)smem;
#pragma unroll
  for (int i = 0; i < 4; ++i)
#pragma unroll
    for (int r = 0; r < 4; ++r){
      int row = wm + i * 16 + quad * 4 + r;
#pragma unroll
      for (int jj = 0; jj < 4; ++jj){
        int col = wn + jj * 16 + lrow;
        int cc = (col >> 3) ^ (row & 15);
        Ct[row * 128 + cc * 8 + (col & 7)] = __float2bfloat16(acc[i][jj][r]);
      }
    }
  __syncthreads();
#pragma unroll
  for (int v = 0; v < 8; ++v){
    int Lr = v * 256 + t;
    int row = Lr >> 4, cc = Lr & 15;
    int cs = cc ^ (row & 15);
    uint4 val = *(const uint4*)(Ct + row * 128 + cs * 8);
    *(uint4*)(y + (size_t)(sbase + row) * CDIM + n0 + cc * 8) = val;
  }
}

// ---------------- combine: out[token] = w0*y[s0] + w1*y[s1] ----------------
__global__ __launch_bounds__(256) void combine_kernel(
    const __hip_bfloat16* __restrict__ y, const int2* __restrict__ token_slots,
    const float* __restrict__ slot_weight, float* __restrict__ out)
{
  int token = blockIdx.x;
  int c = threadIdx.x * 4;
  int2 ss = token_slots[token];
  float w0 = slot_weight[ss.x], w1 = slot_weight[ss.y];
  ushort4 a = *(const ushort4*)((const unsigned short*)y + (size_t)ss.x * CDIM + c);
  ushort4 b = *(const ushort4*)((const unsigned short*)y + (size_t)ss.y * CDIM + c);
  float4 o;
  o.x = w0 * bf2f(a.x) + w1 * bf2f(b.x);
  o.y = w0 * bf2f(a.y) + w1 * bf2f(b.y);
  o.z = w0 * bf2f(a.z) + w1 * bf2f(b.z);
  o.w = w0 * bf2f(a.w) + w1 * bf2f(b.w);
  *(float4*)(out + (size_t)token * CDIM + c) = o;
}

// ---------------- slow-but-correct fallback (ws too small) ----------------
__global__ __launch_bounds__(256) void naive_kernel(
    const float* __restrict__ x, const float* __restrict__ w1, const float* __restrict__ w2,
    const int2* __restrict__ topi, const float2* __restrict__ topw, float* __restrict__ out)
{
  __shared__ float xs[CDIM];
  __shared__ float hs[FDIM];
  int token = blockIdx.x;
  int t = threadIdx.x;
  for (int i = t; i < CDIM; i += 256) xs[i] = x[(size_t)token * CDIM + i];
  float acc[4] = {0.f, 0.f, 0.f, 0.f};
  int2 ei = topi[token]; float2 ew = topw[token];
  int elist[2] = {ei.x, ei.y}; float wlist[2] = {ew.x, ew.y};
  for (int kk = 0; kk < 2; ++kk){
    int e = elist[kk]; float wgt = wlist[kk];
    __syncthreads();
    for (int f = t; f < FDIM; f += 256){
      const float* wcol = w1 + (size_t)e * CDIM * FDIM + f;
      float s = 0.f;
      for (int c = 0; c < CDIM; ++c) s += xs[c] * wcol[(size_t)c * FDIM];
      hs[f] = gelu_exact(s);
    }
    __syncthreads();
    for (int ii = 0; ii < 4; ++ii){
      int c = ii * 256 + t;
      const float* w2col = w2 + (size_t)e * FDIM * CDIM + c;
      float s = 0.f;
      for (int f = 0; f < FDIM; ++f) s += hs[f] * w2col[(size_t)f * CDIM];
      acc[ii] += wgt * s;
    }
  }
  for (int ii = 0; ii < 4; ++ii) out[(size_t)token * CDIM + ii * 256 + t] = acc[ii];
}

extern "C" void kernel_launch(void* const* d_in, const int* in_sizes, int n_in,
                              void* d_out, int out_size, void* d_ws, size_t ws_size,
                              hipStream_t stream)
{
  const float* x  = (const float*)d_in[0];
  const float* gw = (const float*)d_in[1];
  const float* w1 = (const float*)d_in[2];
  const float* w2 = (const float*)d_in[3];
  float* out = (float*)d_out;
  char* ws = (char*)d_ws;

  int*    counts        = (int*)(ws + 0);
  int*    cursors       = (int*)(ws + 32);
  int*    num_tiles     = (int*)(ws + 64);
  int*    tile_expert   = (int*)(ws + 256);
  int*    tile_slotbase = (int*)(ws + 1024);
  int2*   topi          = (int2*)(ws + 4096);
  float2* topw          = (float2*)(ws + 69632);
  int*    slot_token    = (int*)(ws + 135168);
  float*  slot_weight   = (float*)(ws + 204800);
  int2*   token_slots   = (int2*)(ws + 278528);
  const size_t XBF_OFF = 1u << 20;
  const size_t W1T_OFF = XBF_OFF + (size_t)NTOK * CDIM * 2;
  const size_t W2T_OFF = W1T_OFF + (size_t)NUM_EXPERTS * CDIM * FDIM * 2;
  const size_t H_OFF   = W2T_OFF + (size_t)NUM_EXPERTS * CDIM * FDIM * 2;
  const size_t NEED    = H_OFF + (size_t)MAXSLOTS * FDIM * 2;                  // ~295 MB
  __hip_bfloat16* xbf = (__hip_bfloat16*)(ws + XBF_OFF);
  __hip_bfloat16* w1t = (__hip_bfloat16*)(ws + W1T_OFF);
  __hip_bfloat16* w2t = (__hip_bfloat16*)(ws + W2T_OFF);
  __hip_bfloat16* h   = (__hip_bfloat16*)(ws + H_OFF);
  __hip_bfloat16* y   = (__hip_bfloat16*)(ws + W1T_OFF);  // overlays w1t (dead after gemm1)

  hipMemsetAsync(ws, 0, 4096, stream);

  moe_router<<<NTOK / 4, 256, 0, stream>>>(x, gw, topi, topw, counts);

  if (ws_size >= NEED){
    convert_x_kernel<<<NTOK * CDIM / (4 * 256), 256, 0, stream>>>(x, xbf);
    transpose_bf16_kernel<<<dim3(FDIM / 64, CDIM / 64, NUM_EXPERTS), 256, 0, stream>>>(w1, w1t, CDIM, FDIM);
    transpose_bf16_kernel<<<dim3(CDIM / 64, FDIM / 64, NUM_EXPERTS), 256, 0, stream>>>(w2, w2t, FDIM, CDIM);
    scan_kernel<<<1, 256, 0, stream>>>(counts, cursors, num_tiles, tile_expert, tile_slotbase, slot_token, slot_weight);
    assign_kernel<<<NTOK / 256, 256, 0, stream>>>(topi, topw, cursors, slot_token, slot_weight, token_slots);
    gemm1_kernel<<<8 * TILES_PER_XCD * 32, 256, 0, stream>>>(xbf, w1t, h, num_tiles, tile_expert, tile_slotbase, slot_token);
    gemm2_kernel<<<8 * TILES_PER_XCD * 8, 256, 0, stream>>>(h, w2t, y, num_tiles, tile_expert, tile_slotbase);
    combine_kernel<<<NTOK, 256, 0, stream>>>(y, token_slots, slot_weight, out);
  } else {
    naive_kernel<<<NTOK, 256, 0, stream>>>(x, w1, w2, topi, topw, out);
  }
}